// Round 1
// baseline (664.693 us; speedup 1.0000x reference)
//
#include <hip/hip_runtime.h>

#define E_EDGES 1600000
#define N_NODES_ 100000

typedef unsigned short u16;
typedef unsigned int u32;
typedef short bf16x8 __attribute__((ext_vector_type(8)));
typedef float f32x4 __attribute__((ext_vector_type(4)));

__device__ __forceinline__ u16 f2bf(float f){
  u32 u = __builtin_bit_cast(u32, f);
  u += 0x7fffu + ((u >> 16) & 1u);   // round-to-nearest-even
  return (u16)(u >> 16);
}

// Pack 4 (128x128) f32 row-major weight matrices into bf16 B-fragment order:
// frag (n,kc): lane l holds w[kc*32 + (l>>4)*8 + j][n*16 + (l&15)], j=0..7
__global__ void pack4(const float* __restrict__ a, const float* __restrict__ b,
                      const float* __restrict__ c, const float* __restrict__ d,
                      u16* __restrict__ pa, u16* __restrict__ pb,
                      u16* __restrict__ pc, u16* __restrict__ pd){
  int tid = blockIdx.x * 256 + threadIdx.x;   // 0..8191
  int mat = tid >> 11, rem = tid & 2047;
  int n = rem >> 8, k = (rem >> 6) & 3, lane = rem & 63;
  const float* w = mat==0 ? a : mat==1 ? b : mat==2 ? c : d;
  u16* p       = mat==0 ? pa : mat==1 ? pb : mat==2 ? pc : pd;
  int rbase = k*32 + (lane>>4)*8;
  int col   = n*16 + (lane&15);
  int o = ((n*4 + k)*64 + lane)*8;
  #pragma unroll
  for (int j=0;j<8;++j) p[o+j] = f2bf(w[(rbase+j)*128 + col]);
}

// Fused: [stage input] -> L1 fp32 -> (bf16) MFMA L2 -> MFMA L3 -> LayerNorm -> store
template<int IS_EDGE>
__global__ __launch_bounds__(256)
void encoder_kernel(const float* __restrict__ x, const int* __restrict__ eidx,
                    const float* __restrict__ w1, const float* __restrict__ b1,
                    const u16* __restrict__ pw2, const float* __restrict__ b2,
                    const u16* __restrict__ pw3, const float* __restrict__ b3,
                    const float* __restrict__ gw, const float* __restrict__ bw,
                    float* __restrict__ out, long outbase, int nrows, int ntiles)
{
  constexpr int K1  = IS_EDGE ? 4 : 25;
  constexpr int K1P = IS_EDGE ? 4 : 28;   // padded stage pitch (floats)
  constexpr int W1B = K1 * 128 * 4;
  constexpr int INB = 64 * K1P * 4;
  constexpr int OUTB = 64 * 132 * 4;      // f32 out-stage, pitch 132 (bank spread)
  constexpr int UNB = (INB + 32768) > OUTB ? (INB + 32768) : OUTB;
  __shared__ __align__(16) unsigned char smem[W1B + 512 + UNB];
  float* w1s = (float*)smem;
  float* b1s = (float*)(smem + W1B);
  unsigned char* un  = smem + W1B + 512;
  float* in_s = (float*)un;               // [64][K1P] f32
  unsigned char* h1s = un + INB;          // [64][128] bf16, XOR-swizzled 16B slots
  unsigned char* h2s = h1s + 16384;       // same
  float* outs = (float*)un;               // [64][132] f32 (aliases in_s/h1/h2)

  const int tid  = threadIdx.x;
  const int lane = tid & 63, wave = tid >> 6;
  const int li = lane & 15, lg = lane >> 4;

  // resident weight fragments for this wave's 32-col slice (cols [wave*32, wave*32+32))
  bf16x8 B2[2][4], B3[2][4];
  float b2c[2], b3c[2];
  #pragma unroll
  for (int nn=0; nn<2; ++nn){
    int cc = wave*32 + nn*16 + li;
    b2c[nn] = b2[cc]; b3c[nn] = b3[cc];
    #pragma unroll
    for (int kc=0; kc<4; ++kc){
      int o = (((2*wave+nn)*4 + kc)*64 + lane)*8;
      B2[nn][kc] = *(const bf16x8*)(pw2 + o);
      B3[nn][kc] = *(const bf16x8*)(pw3 + o);
    }
  }
  for (int i = tid; i < W1B/16; i += 256)
    ((float4*)w1s)[i] = ((const float4*)w1)[i];
  if (tid < 32) ((float4*)b1s)[tid] = ((const float4*)b1)[tid];

  const f32x4 zv = {0.f, 0.f, 0.f, 0.f};

  for (int tile = blockIdx.x; tile < ntiles; tile += gridDim.x){
    __syncthreads();                       // protect smem reuse across iterations
    const int row0 = tile * 64;

    // ---- stage input rows ----
    if (IS_EDGE){
      if (tid < 64){
        int e = row0 + tid;
        int ir = eidx[e], ic = eidx[E_EDGES + e];
        const float* xr = x + ir*25; const float* xc = x + ic*25;
        float dx = xr[0]-xc[0], dy = xr[1]-xc[1], dz = xr[2]-xc[2];
        float4 v; v.x = dx; v.y = dy; v.z = dz;
        v.w = sqrtf(dx*dx + dy*dy + dz*dz);
        ((float4*)in_s)[tid] = v;
      }
    } else {
      for (int i = tid; i < 64*25; i += 256){
        int r = i / 25, k = i - r*25;
        float v = (row0 + r < nrows) ? x[row0*25 + i] : 0.f;
        in_s[r*K1P + k] = v;
      }
    }
    __syncthreads();

    // ---- layer 1 (fp32 VALU): thread = (row tid>>2, cols (tid&3)*32 .. +31) ----
    {
      const int r = tid >> 2, jb = (tid & 3) * 32;
      float a1[32];
      #pragma unroll
      for (int j=0;j<32;++j) a1[j] = b1s[jb + j];
      for (int k=0;k<K1;++k){
        float xv = in_s[r*K1P + k];
        const float4* wr = (const float4*)(w1s + k*128 + jb);
        #pragma unroll
        for (int j8=0;j8<8;++j8){
          float4 wv = wr[j8];
          a1[j8*4+0] = fmaf(xv, wv.x, a1[j8*4+0]);
          a1[j8*4+1] = fmaf(xv, wv.y, a1[j8*4+1]);
          a1[j8*4+2] = fmaf(xv, wv.z, a1[j8*4+2]);
          a1[j8*4+3] = fmaf(xv, wv.w, a1[j8*4+3]);
        }
      }
      #pragma unroll
      for (int q=0;q<4;++q){
        bf16x8 pk;
        #pragma unroll
        for (int t=0;t<8;++t){
          float v = a1[q*8+t]; v = v > 0.f ? v : 0.f;
          pk[t] = (short)f2bf(v);
        }
        int slot = ((jb>>3) + q) ^ (r & 7);
        *(bf16x8*)(h1s + r*256 + slot*16) = pk;
      }
    }
    __syncthreads();

    // ---- layer 2 (MFMA 16x16x32 bf16) ----
    f32x4 acc[4][2];
    #pragma unroll
    for (int m=0;m<4;++m){ acc[m][0] = zv; acc[m][1] = zv; }
    #pragma unroll
    for (int kc=0;kc<4;++kc){
      bf16x8 A[4];
      #pragma unroll
      for (int m=0;m<4;++m){
        int r = m*16 + li;
        int slot = (lg + kc*4) ^ (r & 7);
        A[m] = *(const bf16x8*)(h1s + r*256 + slot*16);
      }
      #pragma unroll
      for (int m=0;m<4;++m){
        acc[m][0] = __builtin_amdgcn_mfma_f32_16x16x32_bf16(A[m], B2[0][kc], acc[m][0], 0,0,0);
        acc[m][1] = __builtin_amdgcn_mfma_f32_16x16x32_bf16(A[m], B2[1][kc], acc[m][1], 0,0,0);
      }
    }
    // h2 = relu(acc + b2) -> bf16 swizzled LDS
    #pragma unroll
    for (int m=0;m<4;++m){
      #pragma unroll
      for (int nn=0;nn<2;++nn){
        int cc = wave*32 + nn*16 + li;
        #pragma unroll
        for (int j=0;j<4;++j){
          int rr = m*16 + lg*4 + j;
          float v = acc[m][nn][j] + b2c[nn];
          v = v > 0.f ? v : 0.f;
          *(u16*)(h2s + rr*256 + (((cc>>3) ^ (rr&7))<<4) + (cc&7)*2) = f2bf(v);
        }
      }
    }
    __syncthreads();

    // ---- layer 3 (MFMA) ----
    #pragma unroll
    for (int m=0;m<4;++m){ acc[m][0] = zv; acc[m][1] = zv; }
    #pragma unroll
    for (int kc=0;kc<4;++kc){
      bf16x8 A[4];
      #pragma unroll
      for (int m=0;m<4;++m){
        int r = m*16 + li;
        int slot = (lg + kc*4) ^ (r & 7);
        A[m] = *(const bf16x8*)(h2s + r*256 + slot*16);
      }
      #pragma unroll
      for (int m=0;m<4;++m){
        acc[m][0] = __builtin_amdgcn_mfma_f32_16x16x32_bf16(A[m], B3[0][kc], acc[m][0], 0,0,0);
        acc[m][1] = __builtin_amdgcn_mfma_f32_16x16x32_bf16(A[m], B3[1][kc], acc[m][1], 0,0,0);
      }
    }
    __syncthreads();   // all h2 reads done before outs (aliases h2) is written

    #pragma unroll
    for (int m=0;m<4;++m){
      #pragma unroll
      for (int nn=0;nn<2;++nn){
        int cc = wave*32 + nn*16 + li;
        #pragma unroll
        for (int j=0;j<4;++j){
          int rr = m*16 + lg*4 + j;
          outs[rr*132 + cc] = acc[m][nn][j] + b3c[nn];
        }
      }
    }
    __syncthreads();

    // ---- LayerNorm + coalesced store: 4 threads per row ----
    {
      const int r = tid >> 2, cb = (tid & 3) * 32;
      const float* rowp = outs + r*132 + cb;
      float4 hv[8];
      float s = 0.f, sq = 0.f;
      #pragma unroll
      for (int i=0;i<8;++i){
        float4 h = ((const float4*)rowp)[i];
        hv[i] = h;
        s  += h.x + h.y + h.z + h.w;
        sq += h.x*h.x + h.y*h.y + h.z*h.z + h.w*h.w;
      }
      s  += __shfl_xor(s, 1);  sq += __shfl_xor(sq, 1);
      s  += __shfl_xor(s, 2);  sq += __shfl_xor(sq, 2);
      float mu  = s * 0.0078125f;
      float var = sq * 0.0078125f - mu*mu;
      float rs  = rsqrtf(var + 1e-5f);
      int grow = row0 + r;
      if (IS_EDGE || grow < nrows){
        float* op = out + outbase + (long)grow*128 + cb;
        #pragma unroll
        for (int i=0;i<8;++i){
          float4 h  = hv[i];
          float4 gg = ((const float4*)(gw + cb))[i];
          float4 bb = ((const float4*)(bw + cb))[i];
          float4 o;
          o.x = (h.x - mu)*rs*gg.x + bb.x;
          o.y = (h.y - mu)*rs*gg.y + bb.y;
          o.z = (h.z - mu)*rs*gg.z + bb.z;
          o.w = (h.w - mu)*rs*gg.w + bb.w;
          ((float4*)op)[i] = o;
        }
      }
    }
  }
}

extern "C" void kernel_launch(void* const* d_in, const int* in_sizes, int n_in,
                              void* d_out, int out_size, void* d_ws, size_t ws_size,
                              hipStream_t stream){
  const float* x   = (const float*)d_in[0];
  const int*  eidx = (const int*)d_in[1];
  const float* ew1 = (const float*)d_in[2];
  const float* eb1 = (const float*)d_in[3];
  const float* ew2 = (const float*)d_in[4];
  const float* eb2 = (const float*)d_in[5];
  const float* ew3 = (const float*)d_in[6];
  const float* eb3 = (const float*)d_in[7];
  const float* eg  = (const float*)d_in[8];
  const float* ebt = (const float*)d_in[9];
  const float* nw1 = (const float*)d_in[10];
  const float* nb1 = (const float*)d_in[11];
  const float* nw2 = (const float*)d_in[12];
  const float* nb2 = (const float*)d_in[13];
  const float* nw3 = (const float*)d_in[14];
  const float* nb3 = (const float*)d_in[15];
  const float* ng  = (const float*)d_in[16];
  const float* nbt = (const float*)d_in[17];
  float* out = (float*)d_out;

  u16* pew2 = (u16*)d_ws;
  u16* pew3 = pew2 + 16384;
  u16* pnw2 = pew3 + 16384;
  u16* pnw3 = pnw2 + 16384;

  pack4<<<32, 256, 0, stream>>>(ew2, ew3, nw2, nw3, pew2, pew3, pnw2, pnw3);
  encoder_kernel<1><<<2048, 256, 0, stream>>>(x, eidx, ew1, eb1, pew2, eb2, pew3, eb3,
      eg, ebt, out, (long)N_NODES_ * 128, E_EDGES, E_EDGES/64);
  encoder_kernel<0><<<1024, 256, 0, stream>>>(x, nullptr, nw1, nb1, pnw2, nb2, pnw3, nb3,
      ng, nbt, out, 0, N_NODES_, (N_NODES_ + 63)/64);
}

// Round 2
// 576.809 us; speedup vs baseline: 1.1524x; 1.1524x over previous
//
#include <hip/hip_runtime.h>

#define E_EDGES 1600000
#define N_NODES_ 100000

typedef unsigned short u16;
typedef unsigned int u32;
typedef short bf16x8 __attribute__((ext_vector_type(8)));
typedef u16 u16x4 __attribute__((ext_vector_type(4)));
typedef float f32x4 __attribute__((ext_vector_type(4)));

__device__ __forceinline__ u16 f2bf(float f){
  u32 u = __builtin_bit_cast(u32, f);
  u += 0x7fffu + ((u >> 16) & 1u);   // round-to-nearest-even
  return (u16)(u >> 16);
}

// Pack 4 (128x128) f32 row-major weight matrices into bf16 fragment order.
// frag (n,kc): lane l holds w[kc*32 + (l>>4)*8 + j][n*16 + (l&15)], j=0..7.
// Serves as B-operand (cols n*16+li) AND as A-operand of the swapped compute
// (A = W^T slice), since A/B fragment index structure is identical.
__global__ void pack4(const float* __restrict__ a, const float* __restrict__ b,
                      const float* __restrict__ c, const float* __restrict__ d,
                      u16* __restrict__ pa, u16* __restrict__ pb,
                      u16* __restrict__ pc, u16* __restrict__ pd){
  int tid = blockIdx.x * 256 + threadIdx.x;   // 0..8191
  int mat = tid >> 11, rem = tid & 2047;
  int n = rem >> 8, k = (rem >> 6) & 3, lane = rem & 63;
  const float* w = mat==0 ? a : mat==1 ? b : mat==2 ? c : d;
  u16* p       = mat==0 ? pa : mat==1 ? pb : mat==2 ? pc : pd;
  int rbase = k*32 + (lane>>4)*8;
  int col   = n*16 + (lane&15);
  int o = ((n*4 + k)*64 + lane)*8;
  #pragma unroll
  for (int j=0;j<8;++j) p[o+j] = f2bf(w[(rbase+j)*128 + col]);
}

// Fused: stage -> L1 fp32 -> MFMA L2 (swapped) -> MFMA L3 (swapped) -> reg-LN -> store
template<int IS_EDGE>
__global__ __launch_bounds__(256, 4)
void encoder_kernel(const float* __restrict__ x, const int* __restrict__ eidx,
                    const float* __restrict__ w1, const float* __restrict__ b1,
                    const u16* __restrict__ pw2, const float* __restrict__ b2,
                    const u16* __restrict__ pw3, const float* __restrict__ b3,
                    const float* __restrict__ gw, const float* __restrict__ bw,
                    float* __restrict__ out, long outbase, int nrows, int ntiles)
{
  constexpr int K1  = IS_EDGE ? 4 : 25;
  constexpr int K1P = IS_EDGE ? 4 : 26;
  constexpr int W1F = K1 * 128;

  __shared__ __align__(16) float w1s[W1F];
  __shared__ __align__(16) float b1s[128];
  __shared__ __align__(16) float in_s[64*K1P];
  __shared__ __align__(16) unsigned char h1s[16384];  // [64 rows][128 feat] bf16, 16B-slot XOR swizzle
  __shared__ __align__(16) unsigned char h2s[16384];
  __shared__ __align__(16) float pts[64*8];           // LN partials [row][wave*2 + {s,sq}]

  const int tid  = threadIdx.x;
  const int lane = tid & 63, wave = tid >> 6;
  const int li = lane & 15, lg = lane >> 4;
  const int wbase = wave * 32;

  for (int i = tid; i < W1F/4; i += 256)
    ((float4*)w1s)[i] = ((const float4*)w1)[i];
  if (tid < 32) ((float4*)b1s)[tid] = ((const float4*)b1)[tid];

  // ---- gather pipeline regs (edge): 2 tiles ahead on indices, 1 ahead on x rows
  float4 curg = {0.f,0.f,0.f,0.f};
  int ni0 = 0, ni1 = 0;
  float nr0=0,nr1=0,nr2=0,nc0=0,nc1=0,nc2=0;
  if (IS_EDGE && tid < 64){
    int t0 = blockIdx.x;
    if (t0 < ntiles){
      long e = (long)t0*64 + tid;
      int ir = eidx[e], ic = eidx[E_EDGES + e];
      const float* xr = x + (long)ir*25;
      const float* xc = x + (long)ic*25;
      float dx = xr[0]-xc[0], dy = xr[1]-xc[1], dz = xr[2]-xc[2];
      curg.x=dx; curg.y=dy; curg.z=dz; curg.w=sqrtf(dx*dx+dy*dy+dz*dz);
      int t1 = t0 + gridDim.x;
      if (t1 < ntiles){
        long e1 = (long)t1*64 + tid;
        ni0 = eidx[e1]; ni1 = eidx[E_EDGES + e1];
      }
    }
  }

  const f32x4 zv = {0.f,0.f,0.f,0.f};

  for (int tile = blockIdx.x; tile < ntiles; tile += gridDim.x){
    const int row0 = tile * 64;
    const bool hasnext = (tile + (int)gridDim.x) < ntiles;

    // ---- stage input; prefetch next tile's x rows + tile+2's indices ----
    if (IS_EDGE){
      if (tid < 64){
        ((float4*)in_s)[tid] = curg;
        if (hasnext){
          const float* xr = x + (long)ni0*25;
          const float* xc = x + (long)ni1*25;
          nr0=xr[0]; nr1=xr[1]; nr2=xr[2];
          nc0=xc[0]; nc1=xc[1]; nc2=xc[2];
          int t2 = tile + 2*(int)gridDim.x;
          if (t2 < ntiles){
            long e2 = (long)t2*64 + tid;
            ni0 = eidx[e2]; ni1 = eidx[E_EDGES + e2];
          }
        }
      }
    } else {
      for (int i = tid; i < 64*25; i += 256){
        int r = i / 25, k = i - r*25;
        float v = (row0 + r < nrows) ? x[(long)row0*25 + i] : 0.f;
        in_s[r*K1P + k] = v;
      }
    }

    // ---- stream this wave's W2 fragment slice (L1/L2-hot) + b2 ----
    bf16x8 W2f[2][4];
    #pragma unroll
    for (int mt=0;mt<2;++mt)
      #pragma unroll
      for (int kc=0;kc<4;++kc)
        W2f[mt][kc] = *(const bf16x8*)(pw2 + (((wave*2+mt)*4 + kc)*64 + lane)*8);
    f32x4 b2q[2];
    #pragma unroll
    for (int mt=0;mt<2;++mt)
      b2q[mt] = *(const f32x4*)(b2 + wbase + mt*16 + lg*4);

    __syncthreads();   // B1: in_s (and w1s on iter 0) visible

    // ---- layer 1 (fp32 VALU): thread = (row tid>>2, 32 cols) ----
    {
      const int r = tid >> 2, jb = (tid & 3) << 5;
      float a1[32];
      #pragma unroll
      for (int j=0;j<32;++j) a1[j] = b1s[jb + j];
      for (int k=0;k<K1;++k){
        float xv = in_s[r*K1P + k];
        const float4* wr = (const float4*)(w1s + k*128 + jb);
        #pragma unroll
        for (int j8=0;j8<8;++j8){
          float4 wv = wr[j8];
          a1[j8*4+0] = fmaf(xv, wv.x, a1[j8*4+0]);
          a1[j8*4+1] = fmaf(xv, wv.y, a1[j8*4+1]);
          a1[j8*4+2] = fmaf(xv, wv.z, a1[j8*4+2]);
          a1[j8*4+3] = fmaf(xv, wv.w, a1[j8*4+3]);
        }
      }
      #pragma unroll
      for (int q=0;q<4;++q){
        bf16x8 pk;
        #pragma unroll
        for (int t=0;t<8;++t){
          float v = a1[q*8+t]; v = v > 0.f ? v : 0.f;
          pk[t] = (short)f2bf(v);
        }
        *(bf16x8*)(h1s + r*256 + ((((jb>>3)+q) ^ (r&7))<<4)) = pk;
      }
    }
    __syncthreads();   // B2: h1 ready

    // ---- layer 2 (swapped MFMA): D = W2^T * h1^T -> thread holds rows ----
    f32x4 acc[2][4];
    #pragma unroll
    for (int mt=0;mt<2;++mt)
      #pragma unroll
      for (int nt=0;nt<4;++nt) acc[mt][nt] = zv;
    #pragma unroll
    for (int kc=0;kc<4;++kc){
      bf16x8 hf[4];
      #pragma unroll
      for (int nt=0;nt<4;++nt)
        hf[nt] = *(const bf16x8*)(h1s + (nt*16+li)*256 + (((kc*4+lg)^(li&7))<<4));
      #pragma unroll
      for (int mt=0;mt<2;++mt)
        #pragma unroll
        for (int nt=0;nt<4;++nt)
          acc[mt][nt] = __builtin_amdgcn_mfma_f32_16x16x32_bf16(W2f[mt][kc], hf[nt], acc[mt][nt], 0,0,0);
    }

    // ---- stream W3 slice + epilogue params (hide under pack/barrier) ----
    bf16x8 W3f[2][4];
    #pragma unroll
    for (int mt=0;mt<2;++mt)
      #pragma unroll
      for (int kc=0;kc<4;++kc)
        W3f[mt][kc] = *(const bf16x8*)(pw3 + (((wave*2+mt)*4 + kc)*64 + lane)*8);
    f32x4 b3q[2], gq[2], bq[2];
    #pragma unroll
    for (int mt=0;mt<2;++mt){
      b3q[mt] = *(const f32x4*)(b3 + wbase + mt*16 + lg*4);
      gq[mt]  = *(const f32x4*)(gw + wbase + mt*16 + lg*4);
      bq[mt]  = *(const f32x4*)(bw + wbase + mt*16 + lg*4);
    }
    // finish next tile's gather math (regs only, wave 0)
    if (IS_EDGE && tid < 64 && hasnext){
      float dx = nr0-nc0, dy = nr1-nc1, dz = nr2-nc2;
      curg.x=dx; curg.y=dy; curg.z=dz; curg.w=sqrtf(dx*dx+dy*dy+dz*dz);
    }

    // ---- h2 = relu(acc+b2) -> bf16 LDS, one b64 per (mt,nt) ----
    #pragma unroll
    for (int mt=0;mt<2;++mt){
      const int f0 = wbase + mt*16 + lg*4;
      #pragma unroll
      for (int nt=0;nt<4;++nt){
        u16x4 pk;
        #pragma unroll
        for (int j=0;j<4;++j){
          float v = acc[mt][nt][j] + b2q[mt][j];
          v = v > 0.f ? v : 0.f;
          pk[j] = f2bf(v);
        }
        const int r = nt*16 + li;
        *(u16x4*)(h2s + r*256 + (((f0>>3) ^ (r&7))<<4) + ((f0&7)<<1)) = pk;
      }
    }
    __syncthreads();   // B3: h2 ready

    // ---- layer 3 (swapped MFMA) ----
    #pragma unroll
    for (int mt=0;mt<2;++mt)
      #pragma unroll
      for (int nt=0;nt<4;++nt) acc[mt][nt] = zv;
    #pragma unroll
    for (int kc=0;kc<4;++kc){
      bf16x8 hf[4];
      #pragma unroll
      for (int nt=0;nt<4;++nt)
        hf[nt] = *(const bf16x8*)(h2s + (nt*16+li)*256 + (((kc*4+lg)^(li&7))<<4));
      #pragma unroll
      for (int mt=0;mt<2;++mt)
        #pragma unroll
        for (int nt=0;nt<4;++nt)
          acc[mt][nt] = __builtin_amdgcn_mfma_f32_16x16x32_bf16(W3f[mt][kc], hf[nt], acc[mt][nt], 0,0,0);
    }

    // ---- LayerNorm from registers: cross-wave partials via tiny LDS ----
    float sA[4]  = {0.f,0.f,0.f,0.f};
    float sqA[4] = {0.f,0.f,0.f,0.f};
    #pragma unroll
    for (int mt=0;mt<2;++mt)
      #pragma unroll
      for (int nt=0;nt<4;++nt)
        #pragma unroll
        for (int j=0;j<4;++j){
          float v = acc[mt][nt][j] + b3q[mt][j];
          acc[mt][nt][j] = v;
          sA[nt] += v; sqA[nt] += v*v;
        }
    #pragma unroll
    for (int nt=0;nt<4;++nt){
      sA[nt]  += __shfl_xor(sA[nt], 16);  sA[nt]  += __shfl_xor(sA[nt], 32);
      sqA[nt] += __shfl_xor(sqA[nt], 16); sqA[nt] += __shfl_xor(sqA[nt], 32);
    }
    if (lg == 0){
      #pragma unroll
      for (int nt=0;nt<4;++nt){
        pts[(nt*16+li)*8 + wave*2]     = sA[nt];
        pts[(nt*16+li)*8 + wave*2 + 1] = sqA[nt];
      }
    }
    __syncthreads();   // B4: partials ready

    #pragma unroll
    for (int nt=0;nt<4;++nt){
      const int r = nt*16 + li;
      f32x4 p0 = *(const f32x4*)(pts + r*8);
      f32x4 p1 = *(const f32x4*)(pts + r*8 + 4);
      float S  = p0[0]+p0[2]+p1[0]+p1[2];
      float SQ = p0[1]+p0[3]+p1[1]+p1[3];
      float mu = S * 0.0078125f;
      float rs = rsqrtf(SQ*0.0078125f - mu*mu + 1e-5f);
      const int grow = row0 + r;
      if (IS_EDGE || grow < nrows){
        #pragma unroll
        for (int mt=0;mt<2;++mt){
          f32x4 o;
          #pragma unroll
          for (int j=0;j<4;++j)
            o[j] = (acc[mt][nt][j]-mu)*rs*gq[mt][j] + bq[mt][j];
          *(f32x4*)(out + outbase + (long)grow*128 + wbase + mt*16 + lg*4) = o;
        }
      }
    }
  }
}

extern "C" void kernel_launch(void* const* d_in, const int* in_sizes, int n_in,
                              void* d_out, int out_size, void* d_ws, size_t ws_size,
                              hipStream_t stream){
  const float* x   = (const float*)d_in[0];
  const int*  eidx = (const int*)d_in[1];
  const float* ew1 = (const float*)d_in[2];
  const float* eb1 = (const float*)d_in[3];
  const float* ew2 = (const float*)d_in[4];
  const float* eb2 = (const float*)d_in[5];
  const float* ew3 = (const float*)d_in[6];
  const float* eb3 = (const float*)d_in[7];
  const float* eg  = (const float*)d_in[8];
  const float* ebt = (const float*)d_in[9];
  const float* nw1 = (const float*)d_in[10];
  const float* nb1 = (const float*)d_in[11];
  const float* nw2 = (const float*)d_in[12];
  const float* nb2 = (const float*)d_in[13];
  const float* nw3 = (const float*)d_in[14];
  const float* nb3 = (const float*)d_in[15];
  const float* ng  = (const float*)d_in[16];
  const float* nbt = (const float*)d_in[17];
  float* out = (float*)d_out;

  u16* pew2 = (u16*)d_ws;
  u16* pew3 = pew2 + 16384;
  u16* pnw2 = pew3 + 16384;
  u16* pnw3 = pnw2 + 16384;

  pack4<<<32, 256, 0, stream>>>(ew2, ew3, nw2, nw3, pew2, pew3, pnw2, pnw3);
  encoder_kernel<1><<<2048, 256, 0, stream>>>(x, eidx, ew1, eb1, pew2, eb2, pew3, eb3,
      eg, ebt, out, (long)N_NODES_ * 128, E_EDGES, E_EDGES/64);
  encoder_kernel<0><<<1024, 256, 0, stream>>>(x, nullptr, nw1, nb1, pnw2, nb2, pnw3, nb3,
      ng, nbt, out, 0, N_NODES_, (N_NODES_ + 63)/64);
}